// Round 2
// baseline (319.168 us; speedup 1.0000x reference)
//
#include <hip/hip_runtime.h>
#include <math.h>

namespace {

constexpr int Bsz = 16384;
constexpr int T   = 200;
constexpr int F   = 4;
constexpr int H   = 10;

// tanh(x) = 1 - 2/(exp(2x)+1); saturates correctly to +/-1 for |x| large.
__device__ __forceinline__ float fast_tanh(float x) {
  float e = exp2f(x * 2.8853900817779268f);   // exp(2x) via v_exp_f32
  return 1.0f - 2.0f * __builtin_amdgcn_rcpf(e + 1.0f);
}

__device__ __forceinline__ float fast_sigmoid(float x) {
  float e = exp2f(x * -1.4426950408889634f);  // exp(-x)
  return __builtin_amdgcn_rcpf(1.0f + e);
}

__global__ __launch_bounds__(64, 1) void rnn2_reg(
    const float* __restrict__ x,
    const float* __restrict__ W_ih0, const float* __restrict__ W_hh0,
    const float* __restrict__ b_ih0, const float* __restrict__ b_hh0,
    const float* __restrict__ W_ih1, const float* __restrict__ W_hh1,
    const float* __restrict__ b_ih1, const float* __restrict__ b_hh1,
    const float* __restrict__ W_fc, const float* __restrict__ b_fc,
    float* __restrict__ out) {
  // Stage the per-timestep FC weights in LDS (uniform broadcast reads in loop).
  __shared__ float s_wfc[T * H];
  for (int i = threadIdx.x; i < T * H; i += 64) s_wfc[i] = W_fc[i];
  __syncthreads();

  // ---- Force ALL recurrent weights into VGPRs (the round-1 kernel reloaded
  // them from memory every timestep: VGPR_Count was 52, dur 4x the issue
  // floor). ~380 VGPRs with __launch_bounds__(64,1); fully-unrolled constant
  // indices keep them register-allocated.
  float w_ih0[H * F];
#pragma unroll
  for (int i = 0; i < H * F; ++i) w_ih0[i] = W_ih0[i];
  float w_hh0[H * H];
#pragma unroll
  for (int i = 0; i < H * H; ++i) w_hh0[i] = W_hh0[i];
  float w_ih1[H * H];
#pragma unroll
  for (int i = 0; i < H * H; ++i) w_ih1[i] = W_ih1[i];
  float w_hh1[H * H];
#pragma unroll
  for (int i = 0; i < H * H; ++i) w_hh1[i] = W_hh1[i];
  float b0[H], b1[H];
#pragma unroll
  for (int i = 0; i < H; ++i) {
    b0[i] = b_ih0[i] + b_hh0[i];
    b1[i] = b_ih1[i] + b_hh1[i];
  }

  const int b = blockIdx.x * 64 + threadIdx.x;
  const float4* __restrict__ xrow =
      reinterpret_cast<const float4*>(x + (size_t)b * (T * F));

  float h0[H], h1[H];
#pragma unroll
  for (int h = 0; h < H; ++h) { h0[h] = 0.0f; h1[h] = 0.0f; }
  float acc = 0.0f;

  float4 xv = xrow[0];  // current timestep's input (prefetched)
#pragma unroll 1
  for (int t = 0; t < T; ++t) {
    float4 xnext = (t + 1 < T) ? xrow[t + 1] : xv;  // software prefetch

    // layer 0: a0 = b0 + W_ih0 @ x_t + W_hh0 @ h0_prev
    float a0[H];
#pragma unroll
    for (int h = 0; h < H; ++h) {
      float s = b0[h];
      s = fmaf(w_ih0[h * F + 0], xv.x, s);
      s = fmaf(w_ih0[h * F + 1], xv.y, s);
      s = fmaf(w_ih0[h * F + 2], xv.z, s);
      s = fmaf(w_ih0[h * F + 3], xv.w, s);
#pragma unroll
      for (int j = 0; j < H; ++j) s = fmaf(w_hh0[h * H + j], h0[j], s);
      a0[h] = s;
    }
#pragma unroll
    for (int h = 0; h < H; ++h) h0[h] = fast_tanh(a0[h]);

    // layer 1: a1 = b1 + W_ih1 @ h0_new + W_hh1 @ h1_prev
    float a1[H];
#pragma unroll
    for (int h = 0; h < H; ++h) {
      float s = b1[h];
#pragma unroll
      for (int j = 0; j < H; ++j) s = fmaf(w_ih1[h * H + j], h0[j], s);
#pragma unroll
      for (int j = 0; j < H; ++j) s = fmaf(w_hh1[h * H + j], h1[j], s);
      a1[h] = s;
    }
    // update h1 and fuse the FC-head dot product
#pragma unroll
    for (int h = 0; h < H; ++h) {
      float v = fast_tanh(a1[h]);
      h1[h] = v;
      acc = fmaf(v, s_wfc[t * H + h], acc);
    }
    xv = xnext;
  }

  out[b] = fast_sigmoid(acc + b_fc[0]);
}

}  // namespace

extern "C" void kernel_launch(void* const* d_in, const int* in_sizes, int n_in,
                              void* d_out, int out_size, void* d_ws, size_t ws_size,
                              hipStream_t stream) {
  const float* x     = (const float*)d_in[0];
  const float* W_ih0 = (const float*)d_in[1];
  const float* W_hh0 = (const float*)d_in[2];
  const float* b_ih0 = (const float*)d_in[3];
  const float* b_hh0 = (const float*)d_in[4];
  const float* W_ih1 = (const float*)d_in[5];
  const float* W_hh1 = (const float*)d_in[6];
  const float* b_ih1 = (const float*)d_in[7];
  const float* b_hh1 = (const float*)d_in[8];
  const float* b_fc  = (const float*)d_in[10];
  const float* W_fc  = (const float*)d_in[9];
  float* out = (float*)d_out;

  dim3 grid(Bsz / 64), block(64);
  hipLaunchKernelGGL(rnn2_reg, grid, block, 0, stream,
                     x, W_ih0, W_hh0, b_ih0, b_hh0,
                     W_ih1, W_hh1, b_ih1, b_hh1, W_fc, b_fc, out);
}

// Round 3
// 291.950 us; speedup vs baseline: 1.0932x; 1.0932x over previous
//
#include <hip/hip_runtime.h>
#include <math.h>

namespace {

constexpr int Bsz = 16384;
constexpr int T   = 200;
constexpr int F   = 4;
constexpr int H   = 10;

// tanh(x) = 1 - 2/(exp(2x)+1); saturates correctly to +/-1 for |x| large.
__device__ __forceinline__ float fast_tanh(float x) {
  float e = exp2f(x * 2.8853900817779268f);   // exp(2x) via v_exp_f32
  return 1.0f - 2.0f * __builtin_amdgcn_rcpf(e + 1.0f);
}

__device__ __forceinline__ float fast_sigmoid(float x) {
  float e = exp2f(x * -1.4426950408889634f);  // exp(-x)
  return __builtin_amdgcn_rcpf(1.0f + e);
}

// Force a value to be materialized in a VGPR *now*; volatile asm cannot be
// duplicated or sunk into the loop, so the compiler cannot rematerialize the
// load per-iteration (round 1/2 failure mode: VGPR_Count=52, weights reloaded
// every timestep, 4x slowdown from scalar-load latency).
#define PIN_VGPR(v) asm volatile("" : "+v"(v))

__global__ __launch_bounds__(64, 1) void rnn2_pin(
    const float* __restrict__ x,
    const float* __restrict__ W_ih0, const float* __restrict__ W_hh0,
    const float* __restrict__ b_ih0, const float* __restrict__ b_hh0,
    const float* __restrict__ W_ih1, const float* __restrict__ W_hh1,
    const float* __restrict__ b_ih1, const float* __restrict__ b_hh1,
    const float* __restrict__ W_fc, const float* __restrict__ b_fc,
    float* __restrict__ out) {
  // Stage the per-timestep FC weights in LDS (uniform broadcast reads in loop).
  __shared__ float s_wfc[T * H];
  for (int i = threadIdx.x; i < T * H; i += 64) s_wfc[i] = W_fc[i];
  __syncthreads();

  // ---- Load ALL recurrent weights and pin them into VGPRs. ----
  float w_ih0[H * F];
#pragma unroll
  for (int i = 0; i < H * F; ++i) { w_ih0[i] = W_ih0[i]; PIN_VGPR(w_ih0[i]); }
  float w_hh0[H * H];
#pragma unroll
  for (int i = 0; i < H * H; ++i) { w_hh0[i] = W_hh0[i]; PIN_VGPR(w_hh0[i]); }
  float w_ih1[H * H];
#pragma unroll
  for (int i = 0; i < H * H; ++i) { w_ih1[i] = W_ih1[i]; PIN_VGPR(w_ih1[i]); }
  float w_hh1[H * H];
#pragma unroll
  for (int i = 0; i < H * H; ++i) { w_hh1[i] = W_hh1[i]; PIN_VGPR(w_hh1[i]); }
  float b0[H], b1[H];
#pragma unroll
  for (int i = 0; i < H; ++i) {
    b0[i] = b_ih0[i] + b_hh0[i]; PIN_VGPR(b0[i]);
    b1[i] = b_ih1[i] + b_hh1[i]; PIN_VGPR(b1[i]);
  }

  const int b = blockIdx.x * 64 + threadIdx.x;
  const float4* __restrict__ xrow =
      reinterpret_cast<const float4*>(x + (size_t)b * (T * F));

  float h0[H], h1[H];
#pragma unroll
  for (int h = 0; h < H; ++h) { h0[h] = 0.0f; h1[h] = 0.0f; }
  float acc = 0.0f;

  float4 xv = xrow[0];  // current timestep's input (prefetched)
#pragma unroll 1
  for (int t = 0; t < T; ++t) {
    float4 xnext = (t + 1 < T) ? xrow[t + 1] : xv;  // software prefetch

    // layer 0: a0 = b0 + W_ih0 @ x_t + W_hh0 @ h0_prev
    float a0[H];
#pragma unroll
    for (int h = 0; h < H; ++h) {
      float s = b0[h];
      s = fmaf(w_ih0[h * F + 0], xv.x, s);
      s = fmaf(w_ih0[h * F + 1], xv.y, s);
      s = fmaf(w_ih0[h * F + 2], xv.z, s);
      s = fmaf(w_ih0[h * F + 3], xv.w, s);
#pragma unroll
      for (int j = 0; j < H; ++j) s = fmaf(w_hh0[h * H + j], h0[j], s);
      a0[h] = s;
    }
#pragma unroll
    for (int h = 0; h < H; ++h) h0[h] = fast_tanh(a0[h]);

    // layer 1: a1 = b1 + W_ih1 @ h0_new + W_hh1 @ h1_prev
    float a1[H];
#pragma unroll
    for (int h = 0; h < H; ++h) {
      float s = b1[h];
#pragma unroll
      for (int j = 0; j < H; ++j) s = fmaf(w_ih1[h * H + j], h0[j], s);
#pragma unroll
      for (int j = 0; j < H; ++j) s = fmaf(w_hh1[h * H + j], h1[j], s);
      a1[h] = s;
    }
    // update h1 and fuse the FC-head dot product
#pragma unroll
    for (int h = 0; h < H; ++h) {
      float v = fast_tanh(a1[h]);
      h1[h] = v;
      acc = fmaf(v, s_wfc[t * H + h], acc);
    }
    xv = xnext;
  }

  out[b] = fast_sigmoid(acc + b_fc[0]);
}

}  // namespace

extern "C" void kernel_launch(void* const* d_in, const int* in_sizes, int n_in,
                              void* d_out, int out_size, void* d_ws, size_t ws_size,
                              hipStream_t stream) {
  const float* x     = (const float*)d_in[0];
  const float* W_ih0 = (const float*)d_in[1];
  const float* W_hh0 = (const float*)d_in[2];
  const float* b_ih0 = (const float*)d_in[3];
  const float* b_hh0 = (const float*)d_in[4];
  const float* W_ih1 = (const float*)d_in[5];
  const float* W_hh1 = (const float*)d_in[6];
  const float* b_ih1 = (const float*)d_in[7];
  const float* b_hh1 = (const float*)d_in[8];
  const float* W_fc  = (const float*)d_in[9];
  const float* b_fc  = (const float*)d_in[10];
  float* out = (float*)d_out;

  dim3 grid(Bsz / 64), block(64);
  hipLaunchKernelGGL(rnn2_pin, grid, block, 0, stream,
                     x, W_ih0, W_hh0, b_ih0, b_hh0,
                     W_ih1, W_hh1, b_ih1, b_hh1, W_fc, b_fc, out);
}

// Round 4
// 96.864 us; speedup vs baseline: 3.2950x; 3.0140x over previous
//
#include <hip/hip_runtime.h>
#include <math.h>

namespace {

constexpr int Bsz = 16384;
constexpr int T   = 200;
constexpr int F   = 4;
constexpr int H   = 10;
constexpr int HP  = 12;   // hidden padded to 12 = 3 units x 4 lanes
constexpr int BLOCK = 256;

// tanh(x) = 1 - 2/(exp(2x)+1); saturates correctly to +/-1 for |x| large.
__device__ __forceinline__ float fast_tanh(float x) {
  float e = exp2f(x * 2.8853900817779268f);   // exp(2x) via v_exp_f32
  return 1.0f - 2.0f * __builtin_amdgcn_rcpf(e + 1.0f);
}

__device__ __forceinline__ float fast_sigmoid(float x) {
  float e = exp2f(x * -1.4426950408889634f);  // exp(-x)
  return __builtin_amdgcn_rcpf(1.0f + e);
}

// Broadcast lane K (0..3) of each quad to all 4 lanes — v_mov_b32_dpp
// quad_perm, full-rate VALU, no LDS traffic.
template <int K>
__device__ __forceinline__ float qb(float v) {
  return __int_as_float(__builtin_amdgcn_mov_dpp(
      __float_as_int(v), K * 0x55, 0xF, 0xF, true));
}

// Pin a value into a VGPR; volatile asm can't be duplicated/sunk, so the
// compiler cannot re-load it inside the t-loop (rounds 1-3 failure mode).
#define PIN(v) asm volatile("" : "+v"(v))

__global__ __launch_bounds__(BLOCK, 1) void rnn2_quad(
    const float* __restrict__ x,
    const float* __restrict__ W_ih0, const float* __restrict__ W_hh0,
    const float* __restrict__ b_ih0, const float* __restrict__ b_hh0,
    const float* __restrict__ W_ih1, const float* __restrict__ W_hh1,
    const float* __restrict__ b_ih1, const float* __restrict__ b_hh1,
    const float* __restrict__ W_fc, const float* __restrict__ b_fc,
    float* __restrict__ out) {
  // FC weights in LDS, padded to HP floats per timestep (pad = 0).
  __shared__ float s_wfc[T * HP];
  for (int i = threadIdx.x; i < T * HP; i += BLOCK) {
    int t = i / HP, u = i % HP;
    s_wfc[i] = (u < H) ? W_fc[t * H + u] : 0.0f;
  }
  __syncthreads();

  const int g  = blockIdx.x * BLOCK + threadIdx.x;
  const int b  = g >> 2;        // batch element
  const int l  = g & 3;         // quad lane
  const int u0 = l * 3;         // my first hidden unit (pads: u >= 10)

  // ---- my 3 units' weights, zero-padded, pinned into VGPRs (~108 floats) ---
  float wi0[3][F], wh0[3][H], wi1[3][H], wh1[3][H], bb0[3], bb1[3];
#pragma unroll
  for (int k = 0; k < 3; ++k) {
    const int u = u0 + k;
    const bool valid = (u < H);
#pragma unroll
    for (int j = 0; j < F; ++j) { wi0[k][j] = valid ? W_ih0[u * F + j] : 0.0f; PIN(wi0[k][j]); }
#pragma unroll
    for (int j = 0; j < H; ++j) { wh0[k][j] = valid ? W_hh0[u * H + j] : 0.0f; PIN(wh0[k][j]); }
#pragma unroll
    for (int j = 0; j < H; ++j) { wi1[k][j] = valid ? W_ih1[u * H + j] : 0.0f; PIN(wi1[k][j]); }
#pragma unroll
    for (int j = 0; j < H; ++j) { wh1[k][j] = valid ? W_hh1[u * H + j] : 0.0f; PIN(wh1[k][j]); }
    bb0[k] = valid ? (b_ih0[u] + b_hh0[u]) : 0.0f; PIN(bb0[k]);
    bb1[k] = valid ? (b_ih1[u] + b_hh1[u]) : 0.0f; PIN(bb1[k]);
  }

  const float4* __restrict__ xrow =
      reinterpret_cast<const float4*>(x + (size_t)b * (T * F));

  float h0b[H], h1b[H];   // full broadcast h-vectors (units 0..9)
#pragma unroll
  for (int j = 0; j < H; ++j) { h0b[j] = 0.0f; h1b[j] = 0.0f; }
  float acc = 0.0f;

  float4 xv = xrow[0];
#pragma unroll 1
  for (int t = 0; t < T; ++t) {
    float4 xn = (t + 1 < T) ? xrow[t + 1] : xv;  // software prefetch

    // ---- layer 0, my 3 units ----
    float a0, a1v, a2;
    {
      float s0 = bb0[0], s1 = bb0[1], s2 = bb0[2];
      s0 = fmaf(wi0[0][0], xv.x, s0); s1 = fmaf(wi0[1][0], xv.x, s1); s2 = fmaf(wi0[2][0], xv.x, s2);
      s0 = fmaf(wi0[0][1], xv.y, s0); s1 = fmaf(wi0[1][1], xv.y, s1); s2 = fmaf(wi0[2][1], xv.y, s2);
      s0 = fmaf(wi0[0][2], xv.z, s0); s1 = fmaf(wi0[1][2], xv.z, s1); s2 = fmaf(wi0[2][2], xv.z, s2);
      s0 = fmaf(wi0[0][3], xv.w, s0); s1 = fmaf(wi0[1][3], xv.w, s1); s2 = fmaf(wi0[2][3], xv.w, s2);
#pragma unroll
      for (int j = 0; j < H; ++j) {
        s0 = fmaf(wh0[0][j], h0b[j], s0);
        s1 = fmaf(wh0[1][j], h0b[j], s1);
        s2 = fmaf(wh0[2][j], h0b[j], s2);
      }
      a0 = s0; a1v = s1; a2 = s2;
    }
    float m0 = fast_tanh(a0), m1 = fast_tanh(a1v), m2 = fast_tanh(a2);

    // broadcast new h0 across the quad (10 real units)
    h0b[0] = qb<0>(m0); h0b[1] = qb<0>(m1); h0b[2] = qb<0>(m2);
    h0b[3] = qb<1>(m0); h0b[4] = qb<1>(m1); h0b[5] = qb<1>(m2);
    h0b[6] = qb<2>(m0); h0b[7] = qb<2>(m1); h0b[8] = qb<2>(m2);
    h0b[9] = qb<3>(m0);

    // ---- layer 1, my 3 units ----
    {
      float s0 = bb1[0], s1 = bb1[1], s2 = bb1[2];
#pragma unroll
      for (int j = 0; j < H; ++j) {
        s0 = fmaf(wi1[0][j], h0b[j], s0);
        s1 = fmaf(wi1[1][j], h0b[j], s1);
        s2 = fmaf(wi1[2][j], h0b[j], s2);
      }
#pragma unroll
      for (int j = 0; j < H; ++j) {
        s0 = fmaf(wh1[0][j], h1b[j], s0);
        s1 = fmaf(wh1[1][j], h1b[j], s1);
        s2 = fmaf(wh1[2][j], h1b[j], s2);
      }
      a0 = s0; a1v = s1; a2 = s2;
    }
    m0 = fast_tanh(a0); m1 = fast_tanh(a1v); m2 = fast_tanh(a2);

    // FC head contribution for my units (pads read 0 from LDS)
    acc = fmaf(m0, s_wfc[t * HP + u0 + 0], acc);
    acc = fmaf(m1, s_wfc[t * HP + u0 + 1], acc);
    acc = fmaf(m2, s_wfc[t * HP + u0 + 2], acc);

    // broadcast new h1 across the quad
    h1b[0] = qb<0>(m0); h1b[1] = qb<0>(m1); h1b[2] = qb<0>(m2);
    h1b[3] = qb<1>(m0); h1b[4] = qb<1>(m1); h1b[5] = qb<1>(m2);
    h1b[6] = qb<2>(m0); h1b[7] = qb<2>(m1); h1b[8] = qb<2>(m2);
    h1b[9] = qb<3>(m0);

    xv = xn;
  }

  // quad-reduce the FC accumulator
  acc += __shfl_xor(acc, 1);
  acc += __shfl_xor(acc, 2);
  if (l == 0) out[b] = fast_sigmoid(acc + b_fc[0]);
}

}  // namespace

extern "C" void kernel_launch(void* const* d_in, const int* in_sizes, int n_in,
                              void* d_out, int out_size, void* d_ws, size_t ws_size,
                              hipStream_t stream) {
  const float* x     = (const float*)d_in[0];
  const float* W_ih0 = (const float*)d_in[1];
  const float* W_hh0 = (const float*)d_in[2];
  const float* b_ih0 = (const float*)d_in[3];
  const float* b_hh0 = (const float*)d_in[4];
  const float* W_ih1 = (const float*)d_in[5];
  const float* W_hh1 = (const float*)d_in[6];
  const float* b_ih1 = (const float*)d_in[7];
  const float* b_hh1 = (const float*)d_in[8];
  const float* W_fc  = (const float*)d_in[9];
  const float* b_fc  = (const float*)d_in[10];
  float* out = (float*)d_out;

  dim3 grid((Bsz * 4) / BLOCK), block(BLOCK);
  hipLaunchKernelGGL(rnn2_quad, grid, block, 0, stream,
                     x, W_ih0, W_hh0, b_ih0, b_hh0,
                     W_ih1, W_hh1, b_ih1, b_hh1, W_fc, b_fc, out);
}